// Round 1
// 886.438 us; speedup vs baseline: 1.1592x; 1.1592x over previous
//
#include <hip/hip_runtime.h>
#include <math.h>

// ============================================================================
// GQA block: out = Attn(x Wq, x Wk, x Wv) Wo
// I/O: fp32 (per reference). Internal: bf16 MFMA, fp32 accumulate.
//
// Memory plan (ws <= 64 MiB; d_out [64 MiB fp32] doubles as bf16 scratch,
// all scratch dead before the final GEMM rewrites d_out):
//   ws[0,32M)    : wq^T bf16, later wo^T bf16
//   ws[32M,64M)  : Q bf16, then attn-out bf16 (flash writes in place)
//   d_out[0,32M)  : x bf16
//   d_out[32,40M) : wk^T bf16   (dead after K GEMM)
//   d_out[40,48M) : wv^T bf16   (dead after V GEMM)
//   d_out[48,56M) : K bf16      (dead after flash)
//   d_out[56,64M) : V^T bf16    (dead after flash)
// ============================================================================

typedef unsigned short u16;
typedef unsigned int u32;
typedef __bf16 bf16x8 __attribute__((ext_vector_type(8)));
typedef float f32x4 __attribute__((ext_vector_type(4)));
typedef float f32x16 __attribute__((ext_vector_type(16)));
typedef unsigned short u16x8 __attribute__((ext_vector_type(8)));
typedef unsigned short u16x4 __attribute__((ext_vector_type(4)));

#define MFMA16(a, b, c) __builtin_amdgcn_mfma_f32_16x16x32_bf16((a), (b), (c), 0, 0, 0)
#define MFMA32(a, b, c) __builtin_amdgcn_mfma_f32_32x32x16_bf16((a), (b), (c), 0, 0, 0)

// async global->LDS, 16 B per lane; LDS dest = wave-uniform base + lane*16.
#define GLDS(gp, lp)                                                      \
  __builtin_amdgcn_global_load_lds(                                       \
      (const __attribute__((address_space(1))) unsigned int*)(gp),        \
      (__attribute__((address_space(3))) unsigned int*)(lp), 16, 0, 0)

__device__ __forceinline__ u16 f2b(float f) {  // fp32 -> bf16, RNE
  unsigned b = __float_as_uint(f);
  b += 0x7fffu + ((b >> 16) & 1u);
  return (u16)(b >> 16);
}

__device__ __forceinline__ u32 pk2(float a, float b) {  // 2x fp32 -> packed bf16
  union { __bf16 h[2]; u32 w; } u;
  u.h[0] = (__bf16)a;
  u.h[1] = (__bf16)b;
  return u.w;
}

// ---------------------------------------------------------------------------
// Cast fp32 -> bf16, contiguous. 8 elems/thread.
// ---------------------------------------------------------------------------
__global__ __launch_bounds__(256) void cast_f32_bf16(const float* __restrict__ in,
                                                     u16* __restrict__ out, int n) {
  int i = (blockIdx.x * 256 + threadIdx.x) * 8;
  if (i >= n) return;
  f32x4 a = *(const f32x4*)&in[i];
  f32x4 b = *(const f32x4*)&in[i + 4];
  u16x8 v;
#pragma unroll
  for (int j = 0; j < 4; j++) { v[j] = f2b(a[j]); v[4 + j] = f2b(b[j]); }
  *(u16x8*)&out[i] = v;
}

// ---------------------------------------------------------------------------
// Transpose + cast: out[C][R] (bf16) = in[R][C] (fp32). 32x32 LDS tiles.
// ---------------------------------------------------------------------------
__global__ __launch_bounds__(256) void transpose_cast(const float* __restrict__ in,
                                                      u16* __restrict__ out,
                                                      int R, int C) {
  __shared__ u16 t[32][33];
  const int lc = threadIdx.x & 31;
  const int lr = threadIdx.x >> 5;  // 0..7
  const int c0 = blockIdx.x * 32, r0 = blockIdx.y * 32;
#pragma unroll
  for (int i = 0; i < 4; i++) {
    int r = lr + i * 8;
    t[r][lc] = f2b(in[(size_t)(r0 + r) * C + c0 + lc]);
  }
  __syncthreads();
#pragma unroll
  for (int i = 0; i < 4; i++) {
    int r = lr + i * 8;
    out[(size_t)(c0 + r) * R + r0 + lc] = t[lc][r];
  }
}

// ---------------------------------------------------------------------------
// GEMM: C[M,N] = A[M,4096] * BT[N,4096]^T + bias[N].  bf16 in, fp32 acc.
// 128x128 tile, BK=64, 4 waves each 64x64.  m97 pattern: global_load_lds
// width=16 staging into UNPADDED stride-64 LDS.
// STORE_T==1: write C^T ([N][M]) bf16 (for V).  OUT_F32==1: fp32 out (final).
// ---------------------------------------------------------------------------
template <int STORE_T, int OUT_F32>
__global__ __launch_bounds__(256, 2) void gemm_bt(const u16* __restrict__ A,
                                                  const u16* __restrict__ BT,
                                                  const float* __restrict__ bias,
                                                  void* __restrict__ Cv,
                                                  int M, int N) {
  __shared__ u16 As[128][64];  // NO pad: global_load_lds lane order
  __shared__ u16 Bs[128][64];
  const int tid = threadIdx.x;
  const int lane = tid & 63, wave = tid >> 6;
  const int l15 = lane & 15, quad = lane >> 4;
  const int m0 = blockIdx.y * 128, n0 = blockIdx.x * 128;
  const int wm = (wave >> 1) * 64, wn = (wave & 1) * 64;
  const int srow = wave * 32 + (lane >> 3);
  const int scol = (lane & 7) * 8;
  const u16* gA = &A[(size_t)(m0 + srow) * 4096 + scol];
  const u16* gB = &BT[(size_t)(n0 + srow) * 4096 + scol];
  f32x4 acc[4][4] = {};
  for (int kb = 0; kb < 4096; kb += 64) {
    __syncthreads();
#pragma unroll
    for (int j = 0; j < 4; j++) {
      GLDS(gA + (size_t)j * 8 * 4096 + kb, &As[wave * 32 + j * 8][0]);
      GLDS(gB + (size_t)j * 8 * 4096 + kb, &Bs[wave * 32 + j * 8][0]);
    }
    __syncthreads();
#pragma unroll
    for (int ks = 0; ks < 2; ks++) {
      bf16x8 a[4], b[4];
#pragma unroll
      for (int mt = 0; mt < 4; mt++)
        a[mt] = *(const bf16x8*)&As[wm + mt * 16 + l15][ks * 32 + quad * 8];
#pragma unroll
      for (int nt = 0; nt < 4; nt++)
        b[nt] = *(const bf16x8*)&Bs[wn + nt * 16 + l15][ks * 32 + quad * 8];
#pragma unroll
      for (int mt = 0; mt < 4; mt++)
#pragma unroll
        for (int nt = 0; nt < 4; nt++)
          acc[mt][nt] = MFMA16(a[mt], b[nt], acc[mt][nt]);
    }
  }
  float bv[4];
#pragma unroll
  for (int nt = 0; nt < 4; nt++) bv[nt] = bias[n0 + wn + nt * 16 + l15];
#pragma unroll
  for (int mt = 0; mt < 4; mt++) {
    const int row = m0 + wm + mt * 16 + quad * 4;
#pragma unroll
    for (int nt = 0; nt < 4; nt++) {
      const int col = n0 + wn + nt * 16 + l15;
      if (STORE_T) {
        u16x4 v;
#pragma unroll
        for (int r = 0; r < 4; r++) v[r] = f2b(acc[mt][nt][r] + bv[nt]);
        *(u16x4*)&((u16*)Cv)[(size_t)col * M + row] = v;  // 8B store
      } else if (OUT_F32) {
#pragma unroll
        for (int r = 0; r < 4; r++)
          ((float*)Cv)[(size_t)(row + r) * N + col] = acc[mt][nt][r] + bv[nt];
      } else {
#pragma unroll
        for (int r = 0; r < 4; r++)
          ((u16*)Cv)[(size_t)(row + r) * N + col] = f2b(acc[mt][nt][r] + bv[nt]);
      }
    }
  }
}

// ---------------------------------------------------------------------------
// Flash GQA, IN-PLACE: O overwrites Q.  Q:[4096,4096] bf16 (col = h*128+d),
// K:[4096,1024] bf16, VT:[1024,4096] bf16.
//
// m214-style structure: 4 waves x 32 q-rows, KVBLK=64, 32x32x16 MFMA with
// SWAPPED operands for QK^T (S^T = mfma(K,Q)), so the softmax axis (kv) is
// lane-local: col = q = lane&31, row_kv = (reg&3)+8*(reg>>2)+4*(lane>>5).
// Softmax fully in registers (31-op max tree + 1 shfl_xor(32)); P packed to
// bf16 in-register and routed to the PV A-fragment with 8 shfl_xor(32)/tile
// (no P LDS buffer, no fence, ONE barrier per tile).
// K/V staged to XOR-swizzled LDS tiles via global_load_lds with PRE-SWIZZLED
// global source (m173): LDS stays linear, swizzle lives in the source address.
// Swizzle: within each LDS row, 16B-chunk byte ^= ((row&7)<<4) -> the
// column-slice ds_read_b128 spreads across 8 chunk slots (conflict-free).
// Double-buffered: stage(t+1) issued BEFORE compute(t); barrier at tile end
// drains vmcnt (T3 minimum 2-phase).  Defer-max rescale (T13, THR=8 in exp2
// units).  setprio(1) around MFMA clusters (T5).
// LDS = 2*(16K+16K) = 64 KiB -> 2 blocks/CU.
// ---------------------------------------------------------------------------
#define STAGE_KV(bf, t)                                                          \
  {                                                                              \
    _Pragma("unroll") for (int i_ = 0; i_ < 4; i_++) {                           \
      GLDS(gK + (size_t)((t) * 64 + i_ * 4) * 1024 + (offK ^ ((i_ & 1) << 5)),   \
           &KsB[bf][(wave * 16 + i_ * 4) * 128]);                                \
      GLDS(gV + (size_t)(i_ * 8) * 4096 + (t) * 64,                              \
           &VsB[bf][(wave * 32 + i_ * 8) * 64]);                                 \
    }                                                                            \
  }

__global__ __launch_bounds__(256, 2) void flash_gqa(const u16* __restrict__ K,
                                                    const u16* __restrict__ VT,
                                                    u16* __restrict__ QO) {
  __shared__ __align__(16) u16 KsB[2][64 * 128];   // [kv][d], swizzled chunks
  __shared__ __align__(16) u16 VsB[2][128 * 64];   // [d][kv], swizzled chunks
  const int tid = threadIdx.x;
  const int lane = tid & 63, wave = tid >> 6;
  const int l31 = lane & 31, hi = lane >> 5;
  const int bx = blockIdx.x;
  const int qt = bx & 15, h = (bx >> 4) & 31, b = bx >> 9;
  const int hk = h >> 2;  // FACTOR = 4
  const int qrow0 = b * 2048 + qt * 128 + wave * 32;
  const float scl2 = 0.08838834764831845f * 1.4426950408889634f;  // scale*log2e

  // staging source pointers. K rows: wave covers rows [w*16,w*16+16), instr i_
  // -> 4 rows; lane -> row +(lane>>4), chunk lane&15. Source u16 offset within
  // the 128-u16 row slice is (chunk*8) ^ ((row&7)<<3); rows step by 4 per
  // instr, flipping bit2 of row&7 -> offK ^ ((i_&1)<<5).
  const int offK = ((lane & 15) * 8) ^ ((lane >> 4) << 3);
  const u16* gK = &K[(size_t)(b * 2048 + wave * 16 + (lane >> 4)) * 1024 + hk * 128];
  // VT rows (d): wave covers [w*32,w*32+32), instr i_ -> 8 rows; lane -> row
  // +(lane>>3), chunk lane&7; (d&7)=lane>>3 is instr-invariant.
  const u16* gV = &VT[(size_t)(hk * 128 + wave * 32 + (lane >> 3)) * 4096 + b * 2048 +
                      (((lane & 7) * 8) ^ ((lane >> 3) << 3))];

  // prologue: stage tile 0 into buffer 0
  STAGE_KV(0, 0);

  // Q resident: B-operand fragments, n=q=l31, k=d=ks*16+hi*8+j
  bf16x8 qf[8];
#pragma unroll
  for (int ks = 0; ks < 8; ks++)
    qf[ks] = *(const bf16x8*)&QO[(size_t)(qrow0 + l31) * 4096 + h * 128 + ks * 16 + hi * 8];

  f32x16 o[4] = {};                    // O: col(d)=dt*32+l31, row(q) by reg map
  float mrun = -3.0e38f, lrun = 0.0f;  // per q-row (lane pair l, l+32 identical)

  __syncthreads();

  for (int t = 0; t < 32; t++) {
    const int bf = t & 1;
    if (t < 31) STAGE_KV(bf ^ 1, t + 1);  // prefetch next tile (in flight thru compute)

    // ---- S^T = mfma(K, Q): col=q=l31, row_kv=(re&3)+8*(re>>2)+4*hi (+32*kvt)
    f32x16 st[2] = {};
    __builtin_amdgcn_s_setprio(1);
#pragma unroll
    for (int ks = 0; ks < 8; ks++) {
#pragma unroll
      for (int kvt = 0; kvt < 2; kvt++) {
        const int row = kvt * 32 + l31;
        bf16x8 kf = *(const bf16x8*)&KsB[bf][row * 128 +
                                            ((ks * 16 + hi * 8) ^ ((row & 7) << 3))];
        st[kvt] = MFMA32(kf, qf[ks], st[kvt]);
      }
    }
    __builtin_amdgcn_s_setprio(0);

    // ---- online softmax, fully in-register (per lane: its q row, 32 kv vals)
    float tm[16];
#pragma unroll
    for (int r = 0; r < 16; r++) tm[r] = fmaxf(st[0][r], st[1][r]);
#pragma unroll
    for (int s = 8; s >= 1; s >>= 1)
#pragma unroll
      for (int r = 0; r < s; r++) tm[r] = fmaxf(tm[r], tm[r + s]);
    float mx = fmaxf(tm[0], __shfl_xor(tm[0], 32, 64));
    const float mxs = mx * scl2;
    if (__any(mxs > mrun + 8.0f)) {  // defer-max (T13): rescale only on growth
      const float mn = fmaxf(mrun, mxs);
      const float alpha = __builtin_amdgcn_exp2f(mrun - mn);
      mrun = mn;
      lrun *= alpha;
#pragma unroll
      for (int re = 0; re < 16; re++) {  // redistribute alpha to O-reg rows
        const float av = __shfl(alpha, (re & 3) + 8 * (re >> 2) + 4 * hi, 64);
#pragma unroll
        for (int dt = 0; dt < 4; dt++) o[dt][re] *= av;
      }
    }
    float rsa[4] = {0.f, 0.f, 0.f, 0.f};
#pragma unroll
    for (int kvt = 0; kvt < 2; kvt++)
#pragma unroll
      for (int r = 0; r < 16; r++) {
        const float p = __builtin_amdgcn_exp2f(fmaf(st[kvt][r], scl2, -mrun));
        st[kvt][r] = p;
        rsa[r & 3] += p;
      }
    float rs = (rsa[0] + rsa[1]) + (rsa[2] + rsa[3]);
    rs += __shfl_xor(rs, 32, 64);
    lrun += rs;

    // ---- pack P to bf16 words and route to PV A-fragments.
    // Source word W[kvt][rp] = (p[2rp], p[2rp+1]); its dest: kvs=2kvt+(rp>>2),
    // dest-lane parity hd=(rp>>1)&1, slot sl=rp&1; frag word index = 2*src_parity+sl.
    u32 W0[8], W1[8];
#pragma unroll
    for (int rp = 0; rp < 8; rp++) {
      W0[rp] = pk2(st[0][2 * rp], st[0][2 * rp + 1]);
      W1[rp] = pk2(st[1][2 * rp], st[1][2 * rp + 1]);
    }
    u32 fw[4][4];
#pragma unroll
    for (int kvs = 0; kvs < 4; kvs++) {
#pragma unroll
      for (int sl = 0; sl < 2; sl++) {
        const u32 wa = (kvs < 2) ? W0[4 * (kvs & 1) + sl] : W1[4 * (kvs & 1) + sl];
        const u32 wb = (kvs < 2) ? W0[4 * (kvs & 1) + 2 + sl] : W1[4 * (kvs & 1) + 2 + sl];
        const u32 own = hi ? wb : wa;           // my word for my own fragment
        const u32 snd = hi ? wa : wb;           // my word for my partner
        const u32 rcv = (u32)__shfl_xor((int)snd, 32, 64);
        fw[kvs][sl] = hi ? rcv : own;           // word slots 0,1: src parity 0
        fw[kvs][2 + sl] = hi ? own : rcv;       // word slots 2,3: src parity 1
      }
    }

    // ---- O += P V  (A=P: m=q=l31, k=kv; B=V^T: n=d=l31-of-row, k=kv)
    __builtin_amdgcn_s_setprio(1);
#pragma unroll
    for (int kvs = 0; kvs < 4; kvs++) {
      union { u32 w[4]; bf16x8 v; } pa;
      pa.w[0] = fw[kvs][0]; pa.w[1] = fw[kvs][1];
      pa.w[2] = fw[kvs][2]; pa.w[3] = fw[kvs][3];
#pragma unroll
      for (int dt = 0; dt < 4; dt++) {
        const int row = dt * 32 + l31;
        bf16x8 vf = *(const bf16x8*)&VsB[bf][row * 64 +
                                            ((kvs * 16 + hi * 8) ^ ((row & 7) << 3))];
        o[dt] = MFMA32(pa.v, vf, o[dt]);
      }
    }
    __builtin_amdgcn_s_setprio(0);

    __syncthreads();  // drains vmcnt: next-tile stage landed; this tile's reads done
  }

  // ---- epilogue: O /= l, store bf16 in place of Q
  const float invl = 1.0f / lrun;
#pragma unroll
  for (int re = 0; re < 16; re++) {
    const int qv = (re & 3) + 8 * (re >> 2) + 4 * hi;
    const float il = __shfl(invl, qv, 64);
    const size_t rowb = (size_t)(qrow0 + qv) * 4096 + h * 128;
#pragma unroll
    for (int dt = 0; dt < 4; dt++)
      QO[rowb + dt * 32 + l31] = f2b(o[dt][re] * il);
  }
}

// ---------------------------------------------------------------------------
extern "C" void kernel_launch(void* const* d_in, const int* in_sizes, int n_in,
                              void* d_out, int out_size, void* d_ws, size_t ws_size,
                              hipStream_t stream) {
  (void)in_sizes; (void)n_in; (void)out_size; (void)ws_size;
  const float* x    = (const float*)d_in[0];
  const float* wq_w = (const float*)d_in[1];
  const float* wq_b = (const float*)d_in[2];
  const float* wk_w = (const float*)d_in[3];
  const float* wk_b = (const float*)d_in[4];
  const float* wv_w = (const float*)d_in[5];
  const float* wv_b = (const float*)d_in[6];
  const float* wo_w = (const float*)d_in[7];
  const float* wo_b = (const float*)d_in[8];
  float* out = (float*)d_out;
  char* ws = (char*)d_ws;
  char* od = (char*)d_out;

  u16* TQ  = (u16*)(ws);             // 32 MiB: wq^T bf16; later wo^T bf16
  u16* QA  = (u16*)(ws + 33554432);  // 32 MiB: Q bf16, then attn-out (in place)
  u16* Xb  = (u16*)(od);             // 32 MiB: x bf16
  u16* TK  = (u16*)(od + 33554432);  //  8 MiB: wk^T bf16
  u16* TV  = (u16*)(od + 41943040);  //  8 MiB: wv^T bf16
  u16* Kb  = (u16*)(od + 50331648);  //  8 MiB: K bf16
  u16* VTb = (u16*)(od + 58720256);  //  8 MiB: V^T bf16

  cast_f32_bf16<<<8192, 256, 0, stream>>>(x, Xb, 16777216);
  transpose_cast<<<dim3(128, 128), 256, 0, stream>>>(wq_w, TQ, 4096, 4096);
  transpose_cast<<<dim3(32, 128), 256, 0, stream>>>(wk_w, TK, 4096, 1024);
  transpose_cast<<<dim3(32, 128), 256, 0, stream>>>(wv_w, TV, 4096, 1024);

  gemm_bt<0, 0><<<dim3(32, 32), 256, 0, stream>>>(Xb, TQ, wq_b, QA, 4096, 4096);
  gemm_bt<0, 0><<<dim3(8, 32), 256, 0, stream>>>(Xb, TK, wk_b, Kb, 4096, 1024);
  gemm_bt<1, 0><<<dim3(8, 32), 256, 0, stream>>>(Xb, TV, wv_b, VTb, 4096, 1024);

  // wo^T into TQ region — stream-ordered after the Q GEMM that read TQ
  transpose_cast<<<dim3(128, 128), 256, 0, stream>>>(wo_w, TQ, 4096, 4096);

  flash_gqa<<<dim3(1024), 256, 0, stream>>>(Kb, VTb, QA);

  // final: reads only ws (QA, TQ) + wo_b; overwrites all of d_out with fp32
  gemm_bt<0, 1><<<dim3(32, 32), 256, 0, stream>>>(QA, TQ, wo_b, out, 4096, 4096);
}

// Round 2
// 876.537 us; speedup vs baseline: 1.1723x; 1.0113x over previous
//
#include <hip/hip_runtime.h>
#include <math.h>

// ============================================================================
// GQA block: out = Attn(x Wq, x Wk, x Wv) Wo
// I/O: fp32 (per reference). Internal: bf16 MFMA, fp32 accumulate.
//
// Memory plan (ws <= 64 MiB; d_out [64 MiB fp32] doubles as bf16 scratch,
// all scratch dead before the final GEMM rewrites d_out):
//   ws[0,32M)    : wq^T bf16, later wo^T bf16
//   ws[32M,64M)  : Q bf16, then attn-out bf16 (flash writes in place)
//   d_out[0,32M)  : x bf16
//   d_out[32,40M) : wk^T bf16   (dead after K GEMM)
//   d_out[40,48M) : wv^T bf16   (dead after V GEMM)
//   d_out[48,56M) : K bf16      (dead after flash)
//   d_out[56,64M) : V^T bf16    (dead after flash)
// ============================================================================

typedef unsigned short u16;
typedef unsigned int u32;
typedef __bf16 bf16x8 __attribute__((ext_vector_type(8)));
typedef float f32x4 __attribute__((ext_vector_type(4)));
typedef float f32x16 __attribute__((ext_vector_type(16)));
typedef unsigned short u16x8 __attribute__((ext_vector_type(8)));
typedef unsigned short u16x4 __attribute__((ext_vector_type(4)));
typedef int i32x2 __attribute__((ext_vector_type(2)));

#define MFMA16(a, b, c) __builtin_amdgcn_mfma_f32_16x16x32_bf16((a), (b), (c), 0, 0, 0)
#define MFMA32(a, b, c) __builtin_amdgcn_mfma_f32_32x32x16_bf16((a), (b), (c), 0, 0, 0)

// async global->LDS, 16 B per lane; LDS dest = wave-uniform base + lane*16.
#define GLDS(gp, lp)                                                      \
  __builtin_amdgcn_global_load_lds(                                       \
      (const __attribute__((address_space(1))) unsigned int*)(gp),        \
      (__attribute__((address_space(3))) unsigned int*)(lp), 16, 0, 0)

__device__ __forceinline__ u16 f2b(float f) {  // fp32 -> bf16, RNE
  unsigned b = __float_as_uint(f);
  b += 0x7fffu + ((b >> 16) & 1u);
  return (u16)(b >> 16);
}

__device__ __forceinline__ u32 pk2(float a, float b) {  // 2x fp32 -> packed bf16
  union { __bf16 h[2]; u32 w; } u;
  u.h[0] = (__bf16)a;
  u.h[1] = (__bf16)b;
  return u.w;
}

// ---------------------------------------------------------------------------
// Cast fp32 -> bf16, contiguous. 8 elems/thread.
// ---------------------------------------------------------------------------
__global__ __launch_bounds__(256) void cast_f32_bf16(const float* __restrict__ in,
                                                     u16* __restrict__ out, int n) {
  int i = (blockIdx.x * 256 + threadIdx.x) * 8;
  if (i >= n) return;
  f32x4 a = *(const f32x4*)&in[i];
  f32x4 b = *(const f32x4*)&in[i + 4];
  u16x8 v;
#pragma unroll
  for (int j = 0; j < 4; j++) { v[j] = f2b(a[j]); v[4 + j] = f2b(b[j]); }
  *(u16x8*)&out[i] = v;
}

// ---------------------------------------------------------------------------
// Transpose + cast: out[C][R] (bf16) = in[R][C] (fp32). 32x32 LDS tiles.
// ---------------------------------------------------------------------------
__global__ __launch_bounds__(256) void transpose_cast(const float* __restrict__ in,
                                                      u16* __restrict__ out,
                                                      int R, int C) {
  __shared__ u16 t[32][33];
  const int lc = threadIdx.x & 31;
  const int lr = threadIdx.x >> 5;  // 0..7
  const int c0 = blockIdx.x * 32, r0 = blockIdx.y * 32;
#pragma unroll
  for (int i = 0; i < 4; i++) {
    int r = lr + i * 8;
    t[r][lc] = f2b(in[(size_t)(r0 + r) * C + c0 + lc]);
  }
  __syncthreads();
#pragma unroll
  for (int i = 0; i < 4; i++) {
    int r = lr + i * 8;
    out[(size_t)(c0 + r) * R + r0 + lc] = t[lc][r];
  }
}

// ---------------------------------------------------------------------------
// GEMM: C[M,N] = A[M,4096] * BT[N,4096]^T + bias[N].  bf16 in, fp32 acc.
// 128x128 tile, BK=64, 4 waves each 64x64.  m97 pattern: global_load_lds
// width=16 staging into UNPADDED stride-64 LDS.
// STORE_T==1: write C^T ([N][M]) bf16 (for V).  OUT_F32==1: fp32 out (final).
// ---------------------------------------------------------------------------
template <int STORE_T, int OUT_F32>
__global__ __launch_bounds__(256, 2) void gemm_bt(const u16* __restrict__ A,
                                                  const u16* __restrict__ BT,
                                                  const float* __restrict__ bias,
                                                  void* __restrict__ Cv,
                                                  int M, int N) {
  __shared__ u16 As[128][64];  // NO pad: global_load_lds lane order
  __shared__ u16 Bs[128][64];
  const int tid = threadIdx.x;
  const int lane = tid & 63, wave = tid >> 6;
  const int l15 = lane & 15, quad = lane >> 4;
  const int m0 = blockIdx.y * 128, n0 = blockIdx.x * 128;
  const int wm = (wave >> 1) * 64, wn = (wave & 1) * 64;
  const int srow = wave * 32 + (lane >> 3);
  const int scol = (lane & 7) * 8;
  const u16* gA = &A[(size_t)(m0 + srow) * 4096 + scol];
  const u16* gB = &BT[(size_t)(n0 + srow) * 4096 + scol];
  f32x4 acc[4][4] = {};
  for (int kb = 0; kb < 4096; kb += 64) {
    __syncthreads();
#pragma unroll
    for (int j = 0; j < 4; j++) {
      GLDS(gA + (size_t)j * 8 * 4096 + kb, &As[wave * 32 + j * 8][0]);
      GLDS(gB + (size_t)j * 8 * 4096 + kb, &Bs[wave * 32 + j * 8][0]);
    }
    __syncthreads();
#pragma unroll
    for (int ks = 0; ks < 2; ks++) {
      bf16x8 a[4], b[4];
#pragma unroll
      for (int mt = 0; mt < 4; mt++)
        a[mt] = *(const bf16x8*)&As[wm + mt * 16 + l15][ks * 32 + quad * 8];
#pragma unroll
      for (int nt = 0; nt < 4; nt++)
        b[nt] = *(const bf16x8*)&Bs[wn + nt * 16 + l15][ks * 32 + quad * 8];
#pragma unroll
      for (int mt = 0; mt < 4; mt++)
#pragma unroll
        for (int nt = 0; nt < 4; nt++)
          acc[mt][nt] = MFMA16(a[mt], b[nt], acc[mt][nt]);
    }
  }
  float bv[4];
#pragma unroll
  for (int nt = 0; nt < 4; nt++) bv[nt] = bias[n0 + wn + nt * 16 + l15];
#pragma unroll
  for (int mt = 0; mt < 4; mt++) {
    const int row = m0 + wm + mt * 16 + quad * 4;
#pragma unroll
    for (int nt = 0; nt < 4; nt++) {
      const int col = n0 + wn + nt * 16 + l15;
      if (STORE_T) {
        u16x4 v;
#pragma unroll
        for (int r = 0; r < 4; r++) v[r] = f2b(acc[mt][nt][r] + bv[nt]);
        *(u16x4*)&((u16*)Cv)[(size_t)col * M + row] = v;  // 8B store
      } else if (OUT_F32) {
#pragma unroll
        for (int r = 0; r < 4; r++)
          ((float*)Cv)[(size_t)(row + r) * N + col] = acc[mt][nt][r] + bv[nt];
      } else {
#pragma unroll
        for (int r = 0; r < 4; r++)
          ((u16*)Cv)[(size_t)(row + r) * N + col] = f2b(acc[mt][nt][r] + bv[nt]);
      }
    }
  }
}

// ---------------------------------------------------------------------------
// Flash GQA, IN-PLACE: O overwrites Q.  Q:[4096,4096] bf16 (col = h*128+d),
// K:[4096,1024] bf16, VT:[1024,4096] bf16.
//
// 4 waves x 32 q-rows, KVBLK=64, swapped-operand 32x32x16 QK^T (S^T =
// mfma(K,Q)): softmax axis lane-local.  In-register softmax; P routed to the
// PV A-fragment with permlane32_swap (T12 — no LDS path, no bpermute).
// K double-buffered (prefetch t+1 at start of t); V SINGLE-buffered: staged
// at tile start, consumed after B1 (latency hides under QK^T+softmax).
// LDS 48 KiB -> 3 blocks/CU (12 waves/CU) for cross-wave MFMA/VALU overlap.
// Two barriers per tile: B1 (V landed, pre-PV), B2 (PV reads done, pre-restage).
// Defer-max rescale (T13, THR=8 in exp2 units).  setprio(1) around MFMA (T5).
// ---------------------------------------------------------------------------
#define STAGE_K(bf, t)                                                         \
  {                                                                            \
    _Pragma("unroll") for (int i_ = 0; i_ < 4; i_++)                           \
      GLDS(gK + (size_t)((t) * 64 + i_ * 4) * 1024 + (offK ^ ((i_ & 1) << 5)), \
           &KsB[bf][(wave * 16 + i_ * 4) * 128]);                              \
  }
#define STAGE_V(t)                                                             \
  {                                                                            \
    _Pragma("unroll") for (int i_ = 0; i_ < 4; i_++)                           \
      GLDS(gV + (size_t)(i_ * 8) * 4096 + (t) * 64,                            \
           &Vs[(wave * 32 + i_ * 8) * 64]);                                    \
  }

__global__ __launch_bounds__(256, 3) void flash_gqa(const u16* __restrict__ K,
                                                    const u16* __restrict__ VT,
                                                    u16* __restrict__ QO) {
  __shared__ __align__(16) u16 KsB[2][64 * 128];  // [kv][d], swizzled chunks
  __shared__ __align__(16) u16 Vs[128 * 64];      // [d][kv], swizzled, single buf
  const int tid = threadIdx.x;
  const int lane = tid & 63, wave = tid >> 6;
  const int l31 = lane & 31, hi = lane >> 5;
  const int bx = blockIdx.x;
  const int qt = bx & 15, h = (bx >> 4) & 31, b = bx >> 9;
  const int hk = h >> 2;  // FACTOR = 4
  const int qrow0 = b * 2048 + qt * 128 + wave * 32;
  const float scl2 = 0.08838834764831845f * 1.4426950408889634f;  // scale*log2e

  // staging source pointers (pre-swizzled global source, m173 pattern).
  const int offK = ((lane & 15) * 8) ^ ((lane >> 4) << 3);
  const u16* gK = &K[(size_t)(b * 2048 + wave * 16 + (lane >> 4)) * 1024 + hk * 128];
  const u16* gV = &VT[(size_t)(hk * 128 + wave * 32 + (lane >> 3)) * 4096 + b * 2048 +
                      (((lane & 7) * 8) ^ ((lane >> 3) << 3))];

  // prologue: stage K tile 0 into buffer 0
  STAGE_K(0, 0);

  // Q resident: B-operand fragments, n=q=l31, k=d=ks*16+hi*8+j
  bf16x8 qf[8];
#pragma unroll
  for (int ks = 0; ks < 8; ks++)
    qf[ks] = *(const bf16x8*)&QO[(size_t)(qrow0 + l31) * 4096 + h * 128 + ks * 16 + hi * 8];

  f32x16 o[4] = {};                    // O: col(d)=dt*32+l31, row(q) by reg map
  float mrun = -3.0e38f, lrun = 0.0f;  // per q-row (lane pair l, l+32 identical)

  __syncthreads();  // drains prologue K0 stage

  for (int t = 0; t < 32; t++) {
    const int bf = t & 1;
    STAGE_V(t);                            // single V buffer (safe: B2 of t-1)
    if (t < 31) STAGE_K(bf ^ 1, t + 1);    // K prefetch into other buffer

    // ---- S^T = mfma(K, Q): col=q=l31, row_kv=(re&3)+8*(re>>2)+4*hi (+32*kvt)
    f32x16 st[2] = {};
    __builtin_amdgcn_s_setprio(1);
#pragma unroll
    for (int ks = 0; ks < 8; ks++) {
#pragma unroll
      for (int kvt = 0; kvt < 2; kvt++) {
        const int row = kvt * 32 + l31;
        bf16x8 kf = *(const bf16x8*)&KsB[bf][row * 128 +
                                            ((ks * 16 + hi * 8) ^ ((row & 7) << 3))];
        st[kvt] = MFMA32(kf, qf[ks], st[kvt]);
      }
    }
    __builtin_amdgcn_s_setprio(0);

    // ---- online softmax, fully in-register (per lane: its q row, 32 kv vals)
    // max tree shaped for v_max3 fusion (T17)
    float m8[8];
#pragma unroll
    for (int r = 0; r < 8; r++)
      m8[r] = fmaxf(fmaxf(fmaxf(st[0][r], st[0][r + 8]), st[1][r]), st[1][r + 8]);
    float mA = fmaxf(fmaxf(m8[0], m8[1]), m8[2]);
    mA = fmaxf(fmaxf(mA, m8[3]), m8[4]);
    mA = fmaxf(fmaxf(mA, m8[5]), m8[6]);
    mA = fmaxf(mA, m8[7]);
    i32x2 mr = __builtin_amdgcn_permlane32_swap(__float_as_int(mA), __float_as_int(mA),
                                                false, false);
    const float mx = fmaxf(__int_as_float(mr[0]), __int_as_float(mr[1]));
    const float mxs = mx * scl2;
    if (__any(mxs > mrun + 8.0f)) {  // defer-max (T13): rescale only on growth
      const float mn = fmaxf(mrun, mxs);
      const float alpha = __builtin_amdgcn_exp2f(mrun - mn);
      mrun = mn;
      lrun *= alpha;
#pragma unroll
      for (int re = 0; re < 16; re++) {  // redistribute alpha to O-reg rows
        const float av = __shfl(alpha, (re & 3) + 8 * (re >> 2) + 4 * hi, 64);
#pragma unroll
        for (int dt = 0; dt < 4; dt++) o[dt][re] *= av;
      }
    }
    float rsa[4] = {0.f, 0.f, 0.f, 0.f};
#pragma unroll
    for (int kvt = 0; kvt < 2; kvt++)
#pragma unroll
      for (int r = 0; r < 16; r++) {
        const float p = __builtin_amdgcn_exp2f(fmaf(st[kvt][r], scl2, -mrun));
        st[kvt][r] = p;
        rsa[r & 3] += p;
      }
    float rs = (rsa[0] + rsa[1]) + (rsa[2] + rsa[3]);
    i32x2 rr = __builtin_amdgcn_permlane32_swap(__float_as_int(rs), __float_as_int(rs),
                                                false, false);
    lrun += __int_as_float(rr[0]) + __int_as_float(rr[1]);

    // ---- pack P to bf16 words and route to PV A-fragments via permlane32_swap.
    u32 W0[8], W1[8];
#pragma unroll
    for (int rp = 0; rp < 8; rp++) {
      W0[rp] = pk2(st[0][2 * rp], st[0][2 * rp + 1]);
      W1[rp] = pk2(st[1][2 * rp], st[1][2 * rp + 1]);
    }
    u32 fw[4][4];
#pragma unroll
    for (int kvs = 0; kvs < 4; kvs++) {
#pragma unroll
      for (int sl = 0; sl < 2; sl++) {
        const u32 wa = (kvs < 2) ? W0[4 * (kvs & 1) + sl] : W1[4 * (kvs & 1) + sl];
        const u32 wb = (kvs < 2) ? W0[4 * (kvs & 1) + 2 + sl] : W1[4 * (kvs & 1) + 2 + sl];
        i32x2 r = __builtin_amdgcn_permlane32_swap((int)wa, (int)wb, false, false);
        fw[kvs][sl] = (u32)r[0];       // {wa[0:31] | wb[0:31]}
        fw[kvs][2 + sl] = (u32)r[1];   // {wa[32:63] | wb[32:63]}
      }
    }

    __syncthreads();  // B1: V[t] landed (vmcnt drained); all waves past Ks reads? (Ks dbuf: no hazard)

    // ---- O += P V  (A=P: m=q=l31, k=kv; B=V^T: n=d=l31-of-row, k=kv)
    __builtin_amdgcn_s_setprio(1);
#pragma unroll
    for (int kvs = 0; kvs < 4; kvs++) {
      union { u32 w[4]; bf16x8 v; } pa;
      pa.w[0] = fw[kvs][0]; pa.w[1] = fw[kvs][1];
      pa.w[2] = fw[kvs][2]; pa.w[3] = fw[kvs][3];
#pragma unroll
      for (int dt = 0; dt < 4; dt++) {
        const int row = dt * 32 + l31;
        bf16x8 vf = *(const bf16x8*)&Vs[row * 64 +
                                        ((kvs * 16 + hi * 8) ^ ((row & 7) << 3))];
        o[dt] = MFMA32(pa.v, vf, o[dt]);
      }
    }
    __builtin_amdgcn_s_setprio(0);

    __syncthreads();  // B2: all PV reads of Vs done; next iter may restage Vs
  }

  // ---- epilogue: O /= l, store bf16 in place of Q
  const float invl = 1.0f / lrun;
#pragma unroll
  for (int re = 0; re < 16; re++) {
    const int qv = (re & 3) + 8 * (re >> 2) + 4 * hi;
    const float il = __shfl(invl, qv, 64);
    const size_t rowb = (size_t)(qrow0 + qv) * 4096 + h * 128;
#pragma unroll
    for (int dt = 0; dt < 4; dt++)
      QO[rowb + dt * 32 + l31] = f2b(o[dt][re] * il);
  }
}

// ---------------------------------------------------------------------------
extern "C" void kernel_launch(void* const* d_in, const int* in_sizes, int n_in,
                              void* d_out, int out_size, void* d_ws, size_t ws_size,
                              hipStream_t stream) {
  (void)in_sizes; (void)n_in; (void)out_size; (void)ws_size;
  const float* x    = (const float*)d_in[0];
  const float* wq_w = (const float*)d_in[1];
  const float* wq_b = (const float*)d_in[2];
  const float* wk_w = (const float*)d_in[3];
  const float* wk_b = (const float*)d_in[4];
  const float* wv_w = (const float*)d_in[5];
  const float* wv_b = (const float*)d_in[6];
  const float* wo_w = (const float*)d_in[7];
  const float* wo_b = (const float*)d_in[8];
  float* out = (float*)d_out;
  char* ws = (char*)d_ws;
  char* od = (char*)d_out;

  u16* TQ  = (u16*)(ws);             // 32 MiB: wq^T bf16; later wo^T bf16
  u16* QA  = (u16*)(ws + 33554432);  // 32 MiB: Q bf16, then attn-out (in place)
  u16* Xb  = (u16*)(od);             // 32 MiB: x bf16
  u16* TK  = (u16*)(od + 33554432);  //  8 MiB: wk^T bf16
  u16* TV  = (u16*)(od + 41943040);  //  8 MiB: wv^T bf16
  u16* Kb  = (u16*)(od + 50331648);  //  8 MiB: K bf16
  u16* VTb = (u16*)(od + 58720256);  //  8 MiB: V^T bf16

  cast_f32_bf16<<<8192, 256, 0, stream>>>(x, Xb, 16777216);
  transpose_cast<<<dim3(128, 128), 256, 0, stream>>>(wq_w, TQ, 4096, 4096);
  transpose_cast<<<dim3(32, 128), 256, 0, stream>>>(wk_w, TK, 4096, 1024);
  transpose_cast<<<dim3(32, 128), 256, 0, stream>>>(wv_w, TV, 4096, 1024);

  gemm_bt<0, 0><<<dim3(32, 32), 256, 0, stream>>>(Xb, TQ, wq_b, QA, 4096, 4096);
  gemm_bt<0, 0><<<dim3(8, 32), 256, 0, stream>>>(Xb, TK, wk_b, Kb, 4096, 1024);
  gemm_bt<1, 0><<<dim3(8, 32), 256, 0, stream>>>(Xb, TV, wv_b, VTb, 4096, 1024);

  // wo^T into TQ region — stream-ordered after the Q GEMM that read TQ
  transpose_cast<<<dim3(128, 128), 256, 0, stream>>>(wo_w, TQ, 4096, 4096);

  flash_gqa<<<dim3(1024), 256, 0, stream>>>(Kb, VTb, QA);

  // final: reads only ws (QA, TQ) + wo_b; overwrites all of d_out with fp32
  gemm_bt<0, 1><<<dim3(32, 32), 256, 0, stream>>>(QA, TQ, wo_b, out, 4096, 4096);
}

// Round 3
// 857.448 us; speedup vs baseline: 1.1984x; 1.0223x over previous
//
#include <hip/hip_runtime.h>
#include <math.h>

// ============================================================================
// GQA block: out = Attn(x Wq, x Wk, x Wv) Wo
// I/O: fp32 (per reference). Internal: bf16 MFMA, fp32 accumulate.
//
// Memory plan (ws <= 64 MiB; d_out [64 MiB fp32] doubles as bf16 scratch,
// all scratch dead before the final GEMM rewrites d_out):
//   ws[0,32M)    : wq^T bf16, later wo^T bf16
//   ws[32M,64M)  : Q bf16, then attn-out bf16 (flash writes in place)
//   d_out[0,32M)  : x bf16
//   d_out[32,40M) : wk^T bf16   (dead after K GEMM)
//   d_out[40,48M) : wv^T bf16   (dead after V GEMM)
//   d_out[48,56M) : K bf16      (dead after flash)
//   d_out[56,64M) : V^T bf16    (dead after flash)
// ============================================================================

typedef unsigned short u16;
typedef unsigned int u32;
typedef __bf16 bf16x8 __attribute__((ext_vector_type(8)));
typedef float f32x4 __attribute__((ext_vector_type(4)));
typedef float f32x16 __attribute__((ext_vector_type(16)));
typedef unsigned short u16x8 __attribute__((ext_vector_type(8)));
typedef unsigned short u16x4 __attribute__((ext_vector_type(4)));
typedef int i32x2 __attribute__((ext_vector_type(2)));

#define MFMA16(a, b, c) __builtin_amdgcn_mfma_f32_16x16x32_bf16((a), (b), (c), 0, 0, 0)
#define MFMA32(a, b, c) __builtin_amdgcn_mfma_f32_32x32x16_bf16((a), (b), (c), 0, 0, 0)

// async global->LDS, 16 B per lane; LDS dest = wave-uniform base + lane*16.
#define GLDS(gp, lp)                                                      \
  __builtin_amdgcn_global_load_lds(                                       \
      (const __attribute__((address_space(1))) unsigned int*)(gp),        \
      (__attribute__((address_space(3))) unsigned int*)(lp), 16, 0, 0)

__device__ __forceinline__ u16 f2b(float f) {  // fp32 -> bf16, RNE
  unsigned b = __float_as_uint(f);
  b += 0x7fffu + ((b >> 16) & 1u);
  return (u16)(b >> 16);
}

__device__ __forceinline__ u32 pk2(float a, float b) {  // 2x fp32 -> packed bf16
  union { __bf16 h[2]; u32 w; } u;
  u.h[0] = (__bf16)a;
  u.h[1] = (__bf16)b;
  return u.w;
}

// ---------------------------------------------------------------------------
// Cast fp32 -> bf16, contiguous. 8 elems/thread.
// ---------------------------------------------------------------------------
__global__ __launch_bounds__(256) void cast_f32_bf16(const float* __restrict__ in,
                                                     u16* __restrict__ out, int n) {
  int i = (blockIdx.x * 256 + threadIdx.x) * 8;
  if (i >= n) return;
  f32x4 a = *(const f32x4*)&in[i];
  f32x4 b = *(const f32x4*)&in[i + 4];
  u16x8 v;
#pragma unroll
  for (int j = 0; j < 4; j++) { v[j] = f2b(a[j]); v[4 + j] = f2b(b[j]); }
  *(u16x8*)&out[i] = v;
}

// ---------------------------------------------------------------------------
// Transpose + cast: out[C][R] (bf16) = in[R][C] (fp32). 32x32 LDS tiles.
// ---------------------------------------------------------------------------
__global__ __launch_bounds__(256) void transpose_cast(const float* __restrict__ in,
                                                      u16* __restrict__ out,
                                                      int R, int C) {
  __shared__ u16 t[32][33];
  const int lc = threadIdx.x & 31;
  const int lr = threadIdx.x >> 5;  // 0..7
  const int c0 = blockIdx.x * 32, r0 = blockIdx.y * 32;
#pragma unroll
  for (int i = 0; i < 4; i++) {
    int r = lr + i * 8;
    t[r][lc] = f2b(in[(size_t)(r0 + r) * C + c0 + lc]);
  }
  __syncthreads();
#pragma unroll
  for (int i = 0; i < 4; i++) {
    int r = lr + i * 8;
    out[(size_t)(c0 + r) * R + r0 + lc] = t[lc][r];
  }
}

// ---------------------------------------------------------------------------
// GEMM: C[M,N] = A[M,4096] * BT[N,4096]^T + bias[N].  bf16 in, fp32 acc.
// 128x128 tile, BK=64, 4 waves each 64x64.  m97 pattern: global_load_lds
// width=16 staging into UNPADDED stride-64 LDS.
// STORE_T==1: write C^T ([N][M]) bf16 (for V).  OUT_F32==1: fp32 out (final).
// ---------------------------------------------------------------------------
template <int STORE_T, int OUT_F32>
__global__ __launch_bounds__(256, 2) void gemm_bt(const u16* __restrict__ A,
                                                  const u16* __restrict__ BT,
                                                  const float* __restrict__ bias,
                                                  void* __restrict__ Cv,
                                                  int M, int N) {
  __shared__ u16 As[128][64];  // NO pad: global_load_lds lane order
  __shared__ u16 Bs[128][64];
  const int tid = threadIdx.x;
  const int lane = tid & 63, wave = tid >> 6;
  const int l15 = lane & 15, quad = lane >> 4;
  const int m0 = blockIdx.y * 128, n0 = blockIdx.x * 128;
  const int wm = (wave >> 1) * 64, wn = (wave & 1) * 64;
  const int srow = wave * 32 + (lane >> 3);
  const int scol = (lane & 7) * 8;
  const u16* gA = &A[(size_t)(m0 + srow) * 4096 + scol];
  const u16* gB = &BT[(size_t)(n0 + srow) * 4096 + scol];
  f32x4 acc[4][4] = {};
  for (int kb = 0; kb < 4096; kb += 64) {
    __syncthreads();
#pragma unroll
    for (int j = 0; j < 4; j++) {
      GLDS(gA + (size_t)j * 8 * 4096 + kb, &As[wave * 32 + j * 8][0]);
      GLDS(gB + (size_t)j * 8 * 4096 + kb, &Bs[wave * 32 + j * 8][0]);
    }
    __syncthreads();
#pragma unroll
    for (int ks = 0; ks < 2; ks++) {
      bf16x8 a[4], b[4];
#pragma unroll
      for (int mt = 0; mt < 4; mt++)
        a[mt] = *(const bf16x8*)&As[wm + mt * 16 + l15][ks * 32 + quad * 8];
#pragma unroll
      for (int nt = 0; nt < 4; nt++)
        b[nt] = *(const bf16x8*)&Bs[wn + nt * 16 + l15][ks * 32 + quad * 8];
#pragma unroll
      for (int mt = 0; mt < 4; mt++)
#pragma unroll
        for (int nt = 0; nt < 4; nt++)
          acc[mt][nt] = MFMA16(a[mt], b[nt], acc[mt][nt]);
    }
  }
  float bv[4];
#pragma unroll
  for (int nt = 0; nt < 4; nt++) bv[nt] = bias[n0 + wn + nt * 16 + l15];
#pragma unroll
  for (int mt = 0; mt < 4; mt++) {
    const int row = m0 + wm + mt * 16 + quad * 4;
#pragma unroll
    for (int nt = 0; nt < 4; nt++) {
      const int col = n0 + wn + nt * 16 + l15;
      if (STORE_T) {
        u16x4 v;
#pragma unroll
        for (int r = 0; r < 4; r++) v[r] = f2b(acc[mt][nt][r] + bv[nt]);
        *(u16x4*)&((u16*)Cv)[(size_t)col * M + row] = v;  // 8B store
      } else if (OUT_F32) {
#pragma unroll
        for (int r = 0; r < 4; r++)
          ((float*)Cv)[(size_t)(row + r) * N + col] = acc[mt][nt][r] + bv[nt];
      } else {
#pragma unroll
        for (int r = 0; r < 4; r++)
          ((u16*)Cv)[(size_t)(row + r) * N + col] = f2b(acc[mt][nt][r] + bv[nt]);
      }
    }
  }
}

// ---------------------------------------------------------------------------
// Flash GQA, IN-PLACE: O overwrites Q.  Q:[4096,4096] bf16 (col = h*128+d),
// K:[4096,1024] bf16, VT:[1024,4096] bf16.
//
// 4 waves x 32 q-rows, KVBLK=64, swapped-operand 32x32x16 QK^T (S^T =
// mfma(K,Q)): softmax axis lane-local.  In-register softmax; P routed to the
// PV A-fragment with permlane32_swap (T12).
// T15 DEFERRED PV: tile t executes QK^T(t) and PV(t-1) back-to-back (both
// MFMA, independent), THEN softmax(t) -> fw.  PV(t-1) reads V buffer (t-1)%3;
// stage(t+1) writes V buffer (t+1)%3 -> V triple-buffered, K double-buffered.
// ONE barrier per tile; prefetch spans the whole tile's compute (the compiler
// drains vmcnt at the barrier, which is exactly when tile t+1 needs the data).
// LDS = K 32K + V 48K = 80 KiB -> 2 blocks/CU.
// All 32 LDS read offsets precomputed in registers (loop-invariant).
// XCD chunk swizzle: blocks sharing a K/V tile land on the same XCD L2.
// Defer-max rescale (T13, THR=8 in exp2 units).  setprio(1) around MFMA (T5).
// ---------------------------------------------------------------------------
#define STAGE_K(kb, tt)                                                        \
  {                                                                            \
    _Pragma("unroll") for (int i_ = 0; i_ < 4; i_++)                           \
      GLDS(gK + (size_t)((tt) * 64 + i_ * 4) * 1024 + (offK ^ ((i_ & 1) << 5)),\
           &KsF[(kb) * 8192 + (wave * 16 + i_ * 4) * 128]);                    \
  }
#define STAGE_V(vb, tt)                                                        \
  {                                                                            \
    _Pragma("unroll") for (int i_ = 0; i_ < 4; i_++)                           \
      GLDS(gV + (size_t)(i_ * 8) * 4096 + (tt) * 64,                           \
           &VsF[(vb) * 8192 + (wave * 32 + i_ * 8) * 64]);                     \
  }

// PV accumulation from fw fragments + V buffer pb (u16-unit base offset)
#define PV_STEP(pb)                                                            \
  {                                                                            \
    __builtin_amdgcn_s_setprio(1);                                             \
    _Pragma("unroll") for (int kvs = 0; kvs < 4; kvs++) {                      \
      union { u32 w[4]; bf16x8 v; } pa;                                        \
      pa.w[0] = fw[kvs][0]; pa.w[1] = fw[kvs][1];                              \
      pa.w[2] = fw[kvs][2]; pa.w[3] = fw[kvs][3];                              \
      _Pragma("unroll") for (int dt = 0; dt < 4; dt++) {                       \
        bf16x8 vf = *(const bf16x8*)&VsF[(pb) * 8192 + vOff[dt][kvs]];         \
        o[dt] = MFMA32(pa.v, vf, o[dt]);                                       \
      }                                                                        \
    }                                                                          \
    __builtin_amdgcn_s_setprio(0);                                             \
  }

__global__ __launch_bounds__(256, 2) void flash_gqa(const u16* __restrict__ K,
                                                    const u16* __restrict__ VT,
                                                    u16* __restrict__ QO) {
  __shared__ __align__(16) u16 KsF[2 * 64 * 128];  // K dbuf [kv][d], swizzled
  __shared__ __align__(16) u16 VsF[3 * 128 * 64];  // V 3-buf [d][kv], swizzled
  const int tid = threadIdx.x;
  const int lane = tid & 63, wave = tid >> 6;
  const int l31 = lane & 31, hi = lane >> 5;
  // XCD chunk swizzle (bijective, 1024 % 8 == 0): same-XCD blocks contiguous.
  const int bx = (blockIdx.x & 7) * 128 + (blockIdx.x >> 3);
  const int qt = bx & 15, h = (bx >> 4) & 31, b = bx >> 9;
  const int hk = h >> 2;  // FACTOR = 4
  const int qrow0 = b * 2048 + qt * 128 + wave * 32;
  const float scl2 = 0.08838834764831845f * 1.4426950408889634f;  // scale*log2e

  // staging source pointers (pre-swizzled global source, m173 pattern).
  const int offK = ((lane & 15) * 8) ^ ((lane >> 4) << 3);
  const u16* gK = &K[(size_t)(b * 2048 + wave * 16 + (lane >> 4)) * 1024 + hk * 128];
  const u16* gV = &VT[(size_t)(hk * 128 + wave * 32 + (lane >> 3)) * 4096 + b * 2048 +
                      (((lane & 7) * 8) ^ ((lane >> 3) << 3))];

  // precomputed swizzled LDS read offsets (u16 units), loop-invariant
  int kOff[2][8], vOff[4][4];
#pragma unroll
  for (int kvt = 0; kvt < 2; kvt++) {
    const int row = kvt * 32 + l31;
#pragma unroll
    for (int ks = 0; ks < 8; ks++)
      kOff[kvt][ks] = row * 128 + ((ks * 16 + hi * 8) ^ ((row & 7) << 3));
  }
#pragma unroll
  for (int dt = 0; dt < 4; dt++) {
    const int row = dt * 32 + l31;
#pragma unroll
    for (int kvs = 0; kvs < 4; kvs++)
      vOff[dt][kvs] = row * 64 + ((kvs * 16 + hi * 8) ^ ((row & 7) << 3));
  }

  // prologue: stage tile 0 (K buf 0, V buf 0)
  STAGE_K(0, 0);
  STAGE_V(0, 0);

  // Q resident: B-operand fragments, n=q=l31, k=d=ks*16+hi*8+j
  bf16x8 qf[8];
#pragma unroll
  for (int ks = 0; ks < 8; ks++)
    qf[ks] = *(const bf16x8*)&QO[(size_t)(qrow0 + l31) * 4096 + h * 128 + ks * 16 + hi * 8];

  f32x16 o[4] = {};                    // O: col(d)=dt*32+l31, row(q) by reg map
  float mrun = -3.0e38f, lrun = 0.0f;  // per q-row (lane pair l, l+32 identical)
  u32 fw[4][4];                        // P fragments of tile t-1 (PV deferred)

  __syncthreads();  // tile-0 stage drained

  for (int t = 0; t < 32; t++) {
    const int kb = t & 1;
    if (t < 31) {                       // prefetch tile t+1 (spans whole tile)
      STAGE_K(kb ^ 1, t + 1);
      STAGE_V((t + 1) % 3, t + 1);
    }

    // ---- S^T = mfma(K, Q): col=q=l31, row_kv=(re&3)+8*(re>>2)+4*hi (+32*kvt)
    f32x16 st[2] = {};
    __builtin_amdgcn_s_setprio(1);
#pragma unroll
    for (int ks = 0; ks < 8; ks++) {
#pragma unroll
      for (int kvt = 0; kvt < 2; kvt++) {
        bf16x8 kf = *(const bf16x8*)&KsF[kb * 8192 + kOff[kvt][ks]];
        st[kvt] = MFMA32(kf, qf[ks], st[kvt]);
      }
    }
    __builtin_amdgcn_s_setprio(0);

    // ---- deferred PV(t-1): independent MFMA chain, fills QK^T/softmax latency
    if (t > 0) PV_STEP((t - 1) % 3);

    // ---- online softmax, fully in-register (per lane: its q row, 32 kv vals)
    float m8[8];
#pragma unroll
    for (int r = 0; r < 8; r++)
      m8[r] = fmaxf(fmaxf(fmaxf(st[0][r], st[0][r + 8]), st[1][r]), st[1][r + 8]);
    float mA = fmaxf(fmaxf(m8[0], m8[1]), m8[2]);
    mA = fmaxf(fmaxf(mA, m8[3]), m8[4]);
    mA = fmaxf(fmaxf(mA, m8[5]), m8[6]);
    mA = fmaxf(mA, m8[7]);
    i32x2 mr = __builtin_amdgcn_permlane32_swap(__float_as_int(mA), __float_as_int(mA),
                                                false, false);
    const float mx = fmaxf(__int_as_float(mr[0]), __int_as_float(mr[1]));
    const float mxs = mx * scl2;
    if (__any(mxs > mrun + 8.0f)) {  // defer-max (T13): rescale only on growth
      const float mn = fmaxf(mrun, mxs);
      const float alpha = __builtin_amdgcn_exp2f(mrun - mn);
      mrun = mn;
      lrun *= alpha;
#pragma unroll
      for (int re = 0; re < 16; re++) {  // redistribute alpha to O-reg rows
        const float av = __shfl(alpha, (re & 3) + 8 * (re >> 2) + 4 * hi, 64);
#pragma unroll
        for (int dt = 0; dt < 4; dt++) o[dt][re] *= av;
      }
    }
    float rsa[4] = {0.f, 0.f, 0.f, 0.f};
#pragma unroll
    for (int kvt = 0; kvt < 2; kvt++)
#pragma unroll
      for (int r = 0; r < 16; r++) {
        const float p = __builtin_amdgcn_exp2f(fmaf(st[kvt][r], scl2, -mrun));
        st[kvt][r] = p;
        rsa[r & 3] += p;
      }
    float rs = (rsa[0] + rsa[1]) + (rsa[2] + rsa[3]);
    i32x2 rr = __builtin_amdgcn_permlane32_swap(__float_as_int(rs), __float_as_int(rs),
                                                false, false);
    lrun += __int_as_float(rr[0]) + __int_as_float(rr[1]);

    // ---- pack P to bf16 words and route to PV A-fragments via permlane32_swap.
    u32 W0[8], W1[8];
#pragma unroll
    for (int rp = 0; rp < 8; rp++) {
      W0[rp] = pk2(st[0][2 * rp], st[0][2 * rp + 1]);
      W1[rp] = pk2(st[1][2 * rp], st[1][2 * rp + 1]);
    }
#pragma unroll
    for (int kvs = 0; kvs < 4; kvs++) {
#pragma unroll
      for (int sl = 0; sl < 2; sl++) {
        const u32 wa = (kvs < 2) ? W0[4 * (kvs & 1) + sl] : W1[4 * (kvs & 1) + sl];
        const u32 wb = (kvs < 2) ? W0[4 * (kvs & 1) + 2 + sl] : W1[4 * (kvs & 1) + 2 + sl];
        i32x2 r = __builtin_amdgcn_permlane32_swap((int)wa, (int)wb, false, false);
        fw[kvs][sl] = (u32)r[0];       // {wa[0:31] | wb[0:31]}
        fw[kvs][2 + sl] = (u32)r[1];   // {wa[32:63] | wb[32:63]}
      }
    }

    __syncthreads();  // drains stage(t+1); all waves done with Ks[kb], Vs[(t-1)%3]
  }

  // ---- final deferred PV(31): V buffer 31 % 3 = 1
  PV_STEP(1);

  // ---- epilogue: O /= l, store bf16 in place of Q
  const float invl = 1.0f / lrun;
#pragma unroll
  for (int re = 0; re < 16; re++) {
    const int qv = (re & 3) + 8 * (re >> 2) + 4 * hi;
    const float il = __shfl(invl, qv, 64);
    const size_t rowb = (size_t)(qrow0 + qv) * 4096 + h * 128;
#pragma unroll
    for (int dt = 0; dt < 4; dt++)
      QO[rowb + dt * 32 + l31] = f2b(o[dt][re] * il);
  }
}

// ---------------------------------------------------------------------------
extern "C" void kernel_launch(void* const* d_in, const int* in_sizes, int n_in,
                              void* d_out, int out_size, void* d_ws, size_t ws_size,
                              hipStream_t stream) {
  (void)in_sizes; (void)n_in; (void)out_size; (void)ws_size;
  const float* x    = (const float*)d_in[0];
  const float* wq_w = (const float*)d_in[1];
  const float* wq_b = (const float*)d_in[2];
  const float* wk_w = (const float*)d_in[3];
  const float* wk_b = (const float*)d_in[4];
  const float* wv_w = (const float*)d_in[5];
  const float* wv_b = (const float*)d_in[6];
  const float* wo_w = (const float*)d_in[7];
  const float* wo_b = (const float*)d_in[8];
  float* out = (float*)d_out;
  char* ws = (char*)d_ws;
  char* od = (char*)d_out;

  u16* TQ  = (u16*)(ws);             // 32 MiB: wq^T bf16; later wo^T bf16
  u16* QA  = (u16*)(ws + 33554432);  // 32 MiB: Q bf16, then attn-out (in place)
  u16* Xb  = (u16*)(od);             // 32 MiB: x bf16
  u16* TK  = (u16*)(od + 33554432);  //  8 MiB: wk^T bf16
  u16* TV  = (u16*)(od + 41943040);  //  8 MiB: wv^T bf16
  u16* Kb  = (u16*)(od + 50331648);  //  8 MiB: K bf16
  u16* VTb = (u16*)(od + 58720256);  //  8 MiB: V^T bf16

  cast_f32_bf16<<<8192, 256, 0, stream>>>(x, Xb, 16777216);
  transpose_cast<<<dim3(128, 128), 256, 0, stream>>>(wq_w, TQ, 4096, 4096);
  transpose_cast<<<dim3(32, 128), 256, 0, stream>>>(wk_w, TK, 4096, 1024);
  transpose_cast<<<dim3(32, 128), 256, 0, stream>>>(wv_w, TV, 4096, 1024);

  gemm_bt<0, 0><<<dim3(32, 32), 256, 0, stream>>>(Xb, TQ, wq_b, QA, 4096, 4096);
  gemm_bt<0, 0><<<dim3(8, 32), 256, 0, stream>>>(Xb, TK, wk_b, Kb, 4096, 1024);
  gemm_bt<1, 0><<<dim3(8, 32), 256, 0, stream>>>(Xb, TV, wv_b, VTb, 4096, 1024);

  // wo^T into TQ region — stream-ordered after the Q GEMM that read TQ
  transpose_cast<<<dim3(128, 128), 256, 0, stream>>>(wo_w, TQ, 4096, 4096);

  flash_gqa<<<dim3(1024), 256, 0, stream>>>(Kb, VTb, QA);

  // final: reads only ws (QA, TQ) + wo_b; overwrites all of d_out with fp32
  gemm_bt<0, 1><<<dim3(32, 32), 256, 0, stream>>>(QA, TQ, wo_b, out, 4096, 4096);
}

// Round 5
// 777.439 us; speedup vs baseline: 1.3218x; 1.1029x over previous
//
#include <hip/hip_runtime.h>
#include <math.h>

// ============================================================================
// GQA block: out = Attn(x Wq, x Wk, x Wv) Wo
// I/O: fp32 (per reference). Internal: bf16 MFMA, fp32 accumulate.
//
// Memory plan (ws <= 64 MiB; d_out [64 MiB fp32] doubles as bf16 scratch,
// all scratch dead before the final GEMM rewrites d_out):
//   ws[0,32M)    : wq^T bf16, later wo^T bf16
//   ws[32M,64M)  : Q bf16, then attn-out bf16 (flash writes in place)
//   d_out[0,32M)  : x bf16
//   d_out[32,40M) : wk^T bf16   (dead after K GEMM)
//   d_out[40,48M) : wv^T bf16   (dead after V GEMM)
//   d_out[48,56M) : K bf16      (dead after flash)
//   d_out[56,64M) : V^T bf16    (dead after flash)
// ============================================================================

typedef unsigned short u16;
typedef unsigned int u32;
typedef __bf16 bf16x8 __attribute__((ext_vector_type(8)));
typedef float f32x4 __attribute__((ext_vector_type(4)));
typedef float f32x16 __attribute__((ext_vector_type(16)));
typedef unsigned short u16x8 __attribute__((ext_vector_type(8)));
typedef unsigned short u16x4 __attribute__((ext_vector_type(4)));
typedef int i32x2 __attribute__((ext_vector_type(2)));

#define MFMA16(a, b, c) __builtin_amdgcn_mfma_f32_16x16x32_bf16((a), (b), (c), 0, 0, 0)
#define MFMA32(a, b, c) __builtin_amdgcn_mfma_f32_32x32x16_bf16((a), (b), (c), 0, 0, 0)

// async global->LDS, 16 B per lane; LDS dest = wave-uniform base + lane*16.
#define GLDS(gp, lp)                                                      \
  __builtin_amdgcn_global_load_lds(                                       \
      (const __attribute__((address_space(1))) unsigned int*)(gp),        \
      (__attribute__((address_space(3))) unsigned int*)(lp), 16, 0, 0)

__device__ __forceinline__ u16 f2b(float f) {  // fp32 -> bf16, RNE
  unsigned b = __float_as_uint(f);
  b += 0x7fffu + ((b >> 16) & 1u);
  return (u16)(b >> 16);
}

__device__ __forceinline__ u32 pk2(float a, float b) {  // 2x fp32 -> packed bf16
  union { __bf16 h[2]; u32 w; } u;
  u.h[0] = (__bf16)a;
  u.h[1] = (__bf16)b;
  return u.w;
}

// ---------------------------------------------------------------------------
// Cast fp32 -> bf16, contiguous. 8 elems/thread.
// ---------------------------------------------------------------------------
__global__ __launch_bounds__(256) void cast_f32_bf16(const float* __restrict__ in,
                                                     u16* __restrict__ out, int n) {
  int i = (blockIdx.x * 256 + threadIdx.x) * 8;
  if (i >= n) return;
  f32x4 a = *(const f32x4*)&in[i];
  f32x4 b = *(const f32x4*)&in[i + 4];
  u16x8 v;
#pragma unroll
  for (int j = 0; j < 4; j++) { v[j] = f2b(a[j]); v[4 + j] = f2b(b[j]); }
  *(u16x8*)&out[i] = v;
}

// ---------------------------------------------------------------------------
// Transpose + cast: out[C][R] (bf16) = in[R][C] (fp32). 32x32 LDS tiles.
// ---------------------------------------------------------------------------
__global__ __launch_bounds__(256) void transpose_cast(const float* __restrict__ in,
                                                      u16* __restrict__ out,
                                                      int R, int C) {
  __shared__ u16 t[32][33];
  const int lc = threadIdx.x & 31;
  const int lr = threadIdx.x >> 5;  // 0..7
  const int c0 = blockIdx.x * 32, r0 = blockIdx.y * 32;
#pragma unroll
  for (int i = 0; i < 4; i++) {
    int r = lr + i * 8;
    t[r][lc] = f2b(in[(size_t)(r0 + r) * C + c0 + lc]);
  }
  __syncthreads();
#pragma unroll
  for (int i = 0; i < 4; i++) {
    int r = lr + i * 8;
    out[(size_t)(c0 + r) * R + r0 + lc] = t[lc][r];
  }
}

// ---------------------------------------------------------------------------
// GEMM (small-N path): C[M,N] = A[M,4096] * BT[N,4096]^T + bias[N].
// 128x128 tile, BK=64, 4 waves.  m97 pattern.  Used for K/V projections
// (N=1024: 256 blocks keeps all CUs busy; a 256^2 tile would idle 3/4).
// STORE_T==1: write C^T ([N][M]) bf16 (for V).
// ---------------------------------------------------------------------------
template <int STORE_T, int OUT_F32>
__global__ __launch_bounds__(256, 2) void gemm_bt(const u16* __restrict__ A,
                                                  const u16* __restrict__ BT,
                                                  const float* __restrict__ bias,
                                                  void* __restrict__ Cv,
                                                  int M, int N) {
  __shared__ u16 As[128][64];  // NO pad: global_load_lds lane order
  __shared__ u16 Bs[128][64];
  const int tid = threadIdx.x;
  const int lane = tid & 63, wave = tid >> 6;
  const int l15 = lane & 15, quad = lane >> 4;
  const int m0 = blockIdx.y * 128, n0 = blockIdx.x * 128;
  const int wm = (wave >> 1) * 64, wn = (wave & 1) * 64;
  const int srow = wave * 32 + (lane >> 3);
  const int scol = (lane & 7) * 8;
  const u16* gA = &A[(size_t)(m0 + srow) * 4096 + scol];
  const u16* gB = &BT[(size_t)(n0 + srow) * 4096 + scol];
  f32x4 acc[4][4] = {};
  for (int kb = 0; kb < 4096; kb += 64) {
    __syncthreads();
#pragma unroll
    for (int j = 0; j < 4; j++) {
      GLDS(gA + (size_t)j * 8 * 4096 + kb, &As[wave * 32 + j * 8][0]);
      GLDS(gB + (size_t)j * 8 * 4096 + kb, &Bs[wave * 32 + j * 8][0]);
    }
    __syncthreads();
#pragma unroll
    for (int ks = 0; ks < 2; ks++) {
      bf16x8 a[4], b[4];
#pragma unroll
      for (int mt = 0; mt < 4; mt++)
        a[mt] = *(const bf16x8*)&As[wm + mt * 16 + l15][ks * 32 + quad * 8];
#pragma unroll
      for (int nt = 0; nt < 4; nt++)
        b[nt] = *(const bf16x8*)&Bs[wn + nt * 16 + l15][ks * 32 + quad * 8];
#pragma unroll
      for (int mt = 0; mt < 4; mt++)
#pragma unroll
        for (int nt = 0; nt < 4; nt++)
          acc[mt][nt] = MFMA16(a[mt], b[nt], acc[mt][nt]);
    }
  }
  float bv[4];
#pragma unroll
  for (int nt = 0; nt < 4; nt++) bv[nt] = bias[n0 + wn + nt * 16 + l15];
#pragma unroll
  for (int mt = 0; mt < 4; mt++) {
    const int row = m0 + wm + mt * 16 + quad * 4;
#pragma unroll
    for (int nt = 0; nt < 4; nt++) {
      const int col = n0 + wn + nt * 16 + l15;
      if (STORE_T) {
        u16x4 v;
#pragma unroll
        for (int r = 0; r < 4; r++) v[r] = f2b(acc[mt][nt][r] + bv[nt]);
        *(u16x4*)&((u16*)Cv)[(size_t)col * M + row] = v;  // 8B store
      } else if (OUT_F32) {
#pragma unroll
        for (int r = 0; r < 4; r++)
          ((float*)Cv)[(size_t)(row + r) * N + col] = acc[mt][nt][r] + bv[nt];
      } else {
#pragma unroll
        for (int r = 0; r < 4; r++)
          ((u16*)Cv)[(size_t)(row + r) * N + col] = f2b(acc[mt][nt][r] + bv[nt]);
      }
    }
  }
}

// ---------------------------------------------------------------------------
// GEMM 256x256 8-phase (big-GEMM path, m201 template): C = A * BT^T + bias.
// M=N=K=4096.  512 thr = 8 waves (2M x 4N), per-wave C = 128x64.  BK=64.
// LDS = 2 bufs x (A 256x64 + B 256x64) bf16 = 128 KiB -> 1 block/CU.
//
// STAGE UNITS ALIGNED WITH READ-PHASE FREES (R4 bug fix):
//   A-unit s = rows {blk*128 + s*64 + [0,64) : blk=0,1}   (what P0/P2 read)
//   B-unit s = rows {q*64  + s*32 + [0,32) : q=0..3}      (what P0/P1 read)
// Reads: P0 = A-s0 + B-s0, P1 = B-s1, P2 = A-s1, P3 = none.
// Stages (each one phase AFTER its region's free):
//   P0: A-s1(u+1) -> next buf (freed at P2 of u-1)
//   P1: A-s0(u+2) -> cur      (freed at P0)
//   P2: B-s0(u+2) -> cur      (freed at P0)
//   P3: B-s1(u+2) -> cur      (freed at P1)
// ONE counted vmcnt per K-tile (T4): at tile end, outstanding = 3 units
// (6 loads) from P1/P2/P3 -> vmcnt(6) guarantees tile u+1 fully landed.
// Prologue: 7 units (tile 0 complete + tile 1's A-s0,B-s0,B-s1), vmcnt(6).
// T2: source-pre-swizzled chunks (c ^= row&7); all ds_read_b128
// column-slices conflict-free.  T5: setprio around MFMA clusters.
// ---------------------------------------------------------------------------
#define STA256(bb, s, tt)                                                     \
  {                                                                           \
    _Pragma("unroll") for (int j_ = 0; j_ < 2; j_++) {                        \
      const int r_ = (w >> 2) * 128 + (s) * 64 + (w & 3) * 16 + j_ * 8;       \
      GLDS(gAu + (size_t)r_ * 4096 + (size_t)(tt) * 64,                       \
           &Lds[((bb) * 2 + 0) * 16384 + r_ * 64]);                           \
    }                                                                         \
  }
#define STB256(bb, s, tt)                                                     \
  {                                                                           \
    _Pragma("unroll") for (int j_ = 0; j_ < 2; j_++) {                        \
      const int r_ = (w >> 1) * 64 + (s) * 32 + (w & 1) * 16 + j_ * 8;        \
      GLDS(gBu + (size_t)r_ * 4096 + (size_t)(tt) * 64,                       \
           &Lds[((bb) * 2 + 1) * 16384 + r_ * 64]);                           \
    }                                                                         \
  }

#define QUAD256(MB, NB)                                                       \
  {                                                                           \
    _Pragma("unroll") for (int mt_ = 0; mt_ < 4; mt_++)                       \
        _Pragma("unroll") for (int nt_ = 0; nt_ < 2; nt_++) {                 \
      acc[(MB) * 4 + mt_][(NB) * 2 + nt_] = MFMA16(                           \
          a[mt_][0], b[(NB) * 2 + nt_][0], acc[(MB) * 4 + mt_][(NB) * 2 + nt_]); \
      acc[(MB) * 4 + mt_][(NB) * 2 + nt_] = MFMA16(                           \
          a[mt_][1], b[(NB) * 2 + nt_][1], acc[(MB) * 4 + mt_][(NB) * 2 + nt_]); \
    }                                                                         \
  }

template <int OUT_F32>
__global__ __launch_bounds__(512, 2) void gemm256(const u16* __restrict__ A,
                                                  const u16* __restrict__ BT,
                                                  const float* __restrict__ bias,
                                                  void* __restrict__ Cv) {
  __shared__ __align__(16) u16 Lds[2 * 2 * 16384];  // [buf][A,B][256*64]
  const int tid = threadIdx.x;
  const int lane = tid & 63, w = tid >> 6;  // 8 waves
  const int l15 = lane & 15, quad = lane >> 4;
  const int wr = w >> 2, wc = w & 3;        // 2M x 4N wave grid
  // XCD chunk swizzle (256 % 8 == 0, bijective)
  const int bid = (blockIdx.x & 7) * 32 + (blockIdx.x >> 3);
  const int m0 = (bid >> 4) * 256, n0 = (bid & 15) * 256;

  // staging source (pre-swizzled chunk; dest row&7 == lane>>3 for all units)
  const int srow = lane >> 3;                       // 0..7
  const int schunk = ((lane & 7) ^ srow) * 8;       // u16 offset in k-block
  const u16* gAu = &A[(size_t)(m0 + srow) * 4096 + schunk];
  const u16* gBu = &BT[(size_t)(n0 + srow) * 4096 + schunk];

  // swizzled ds_read offsets (u16 units); frag (mt,ks) = base + mt*1024
  const int sw0 = ((quad ^ (l15 & 7)) * 8), sw1 = (((4 + quad) ^ (l15 & 7)) * 8);
  const int aoff0 = (wr * 128 + l15) * 64 + sw0, aoff1 = (wr * 128 + l15) * 64 + sw1;
  const int boff0 = (wc * 64 + l15) * 64 + sw0, boff1 = (wc * 64 + l15) * 64 + sw1;

  f32x4 acc[8][4] = {};
  bf16x8 a[4][2], b[4][2];

  // prologue: tile 0 complete + tile 1's first 3 units (steady-state order)
  STA256(0, 0, 0);  // A-s0(0)
  STB256(0, 0, 0);  // B-s0(0)
  STB256(0, 1, 0);  // B-s1(0)
  STA256(0, 1, 0);  // A-s1(0)
  STA256(1, 0, 1);  // A-s0(1)
  STB256(1, 0, 1);  // B-s0(1)
  STB256(1, 1, 1);  // B-s1(1)
  asm volatile("s_waitcnt vmcnt(6)" ::: "memory");  // tile 0 fully landed
  __builtin_amdgcn_s_barrier();

  for (int u = 0; u < 64; u++) {
    const int cur = u & 1;
    const u16* LA = &Lds[(cur * 2 + 0) * 16384];
    const u16* LB = &Lds[(cur * 2 + 1) * 16384];

    // ---- P0: ds A-s0 (8 b128) + B-s0 (4 b128); stage A-s1(u+1) -> next buf
#pragma unroll
    for (int mt = 0; mt < 4; mt++) {
      a[mt][0] = *(const bf16x8*)&LA[aoff0 + mt * 1024];
      a[mt][1] = *(const bf16x8*)&LA[aoff1 + mt * 1024];
    }
#pragma unroll
    for (int nt = 0; nt < 2; nt++) {
      b[nt][0] = *(const bf16x8*)&LB[boff0 + nt * 1024];
      b[nt][1] = *(const bf16x8*)&LB[boff1 + nt * 1024];
    }
    if (u < 63) STA256(cur ^ 1, 1, u + 1);
    __builtin_amdgcn_s_barrier();
    asm volatile("s_waitcnt lgkmcnt(0)" ::: "memory");
    __builtin_amdgcn_s_setprio(1);
    QUAD256(0, 0);
    __builtin_amdgcn_s_setprio(0);
    __builtin_amdgcn_s_barrier();

    // ---- P1: ds B-s1 (4 b128); stage A-s0(u+2) -> cur (freed at P0)
#pragma unroll
    for (int nt = 2; nt < 4; nt++) {
      b[nt][0] = *(const bf16x8*)&LB[boff0 + nt * 1024];
      b[nt][1] = *(const bf16x8*)&LB[boff1 + nt * 1024];
    }
    if (u < 62) STA256(cur, 0, u + 2);
    __builtin_amdgcn_s_barrier();
    asm volatile("s_waitcnt lgkmcnt(0)" ::: "memory");
    __builtin_amdgcn_s_setprio(1);
    QUAD256(0, 1);
    __builtin_amdgcn_s_setprio(0);
    __builtin_amdgcn_s_barrier();

    // ---- P2: ds A-s1 (8 b128, overwrites a[]); stage B-s0(u+2) -> cur
#pragma unroll
    for (int mt = 0; mt < 4; mt++) {
      a[mt][0] = *(const bf16x8*)&LA[aoff0 + (mt + 4) * 1024];
      a[mt][1] = *(const bf16x8*)&LA[aoff1 + (mt + 4) * 1024];
    }
    if (u < 62) STB256(cur, 0, u + 2);
    __builtin_amdgcn_s_barrier();
    asm volatile("s_waitcnt lgkmcnt(0)" ::: "memory");
    __builtin_amdgcn_s_setprio(1);
    QUAD256(1, 0);
    __builtin_amdgcn_s_setprio(0);
    __builtin_amdgcn_s_barrier();

    // ---- P3: no ds reads; stage B-s1(u+2) -> cur (freed at P1)
    if (u < 62) STB256(cur, 1, u + 2);
    __builtin_amdgcn_s_setprio(1);
    QUAD256(1, 1);
    __builtin_amdgcn_s_setprio(0);
    // counted drain (T4): keep 3 units (6 loads) in flight across tiles
    if (u == 62) asm volatile("s_waitcnt vmcnt(0)" ::: "memory");
    else if (u < 62) asm volatile("s_waitcnt vmcnt(6)" ::: "memory");
    if (u < 63) __builtin_amdgcn_s_barrier();
  }

  // ---- epilogue: +bias, store.  C/D: row = quad*4+r, col = l15.
  float bv[4];
#pragma unroll
  for (int nt = 0; nt < 4; nt++) bv[nt] = bias[n0 + wc * 64 + nt * 16 + l15];
#pragma unroll
  for (int mt = 0; mt < 8; mt++) {
    const int row = m0 + wr * 128 + mt * 16 + quad * 4;
#pragma unroll
    for (int nt = 0; nt < 4; nt++) {
      const int col = n0 + wc * 64 + nt * 16 + l15;
      if (OUT_F32) {
#pragma unroll
        for (int r = 0; r < 4; r++)
          ((float*)Cv)[(size_t)(row + r) * 4096 + col] = acc[mt][nt][r] + bv[nt];
      } else {
#pragma unroll
        for (int r = 0; r < 4; r++)
          ((u16*)Cv)[(size_t)(row + r) * 4096 + col] = f2b(acc[mt][nt][r] + bv[nt]);
      }
    }
  }
}

// ---------------------------------------------------------------------------
// Flash GQA, IN-PLACE: O overwrites Q.  (R3 structure, unchanged.)
// ---------------------------------------------------------------------------
#define STAGE_K(kb, tt)                                                        \
  {                                                                            \
    _Pragma("unroll") for (int i_ = 0; i_ < 4; i_++)                           \
      GLDS(gK + (size_t)((tt) * 64 + i_ * 4) * 1024 + (offK ^ ((i_ & 1) << 5)),\
           &KsF[(kb) * 8192 + (wave * 16 + i_ * 4) * 128]);                    \
  }
#define STAGE_V(vb, tt)                                                        \
  {                                                                            \
    _Pragma("unroll") for (int i_ = 0; i_ < 4; i_++)                           \
      GLDS(gV + (size_t)(i_ * 8) * 4096 + (tt) * 64,                           \
           &VsF[(vb) * 8192 + (wave * 32 + i_ * 8) * 64]);                     \
  }

#define PV_STEP(pb)                                                            \
  {                                                                            \
    __builtin_amdgcn_s_setprio(1);                                             \
    _Pragma("unroll") for (int kvs = 0; kvs < 4; kvs++) {                      \
      union { u32 w[4]; bf16x8 v; } pa;                                        \
      pa.w[0] = fw[kvs][0]; pa.w[1] = fw[kvs][1];                              \
      pa.w[2] = fw[kvs][2]; pa.w[3] = fw[kvs][3];                              \
      _Pragma("unroll") for (int dt = 0; dt < 4; dt++) {                       \
        bf16x8 vf = *(const bf16x8*)&VsF[(pb) * 8192 + vOff[dt][kvs]];         \
        o[dt] = MFMA32(pa.v, vf, o[dt]);                                       \
      }                                                                        \
    }                                                                          \
    __builtin_amdgcn_s_setprio(0);                                             \
  }

__global__ __launch_bounds__(256, 2) void flash_gqa(const u16* __restrict__ K,
                                                    const u16* __restrict__ VT,
                                                    u16* __restrict__ QO) {
  __shared__ __align__(16) u16 KsF[2 * 64 * 128];  // K dbuf [kv][d], swizzled
  __shared__ __align__(16) u16 VsF[3 * 128 * 64];  // V 3-buf [d][kv], swizzled
  const int tid = threadIdx.x;
  const int lane = tid & 63, wave = tid >> 6;
  const int l31 = lane & 31, hi = lane >> 5;
  const int bx = (blockIdx.x & 7) * 128 + (blockIdx.x >> 3);
  const int qt = bx & 15, h = (bx >> 4) & 31, b = bx >> 9;
  const int hk = h >> 2;  // FACTOR = 4
  const int qrow0 = b * 2048 + qt * 128 + wave * 32;
  const float scl2 = 0.08838834764831845f * 1.4426950408889634f;  // scale*log2e

  const int offK = ((lane & 15) * 8) ^ ((lane >> 4) << 3);
  const u16* gK = &K[(size_t)(b * 2048 + wave * 16 + (lane >> 4)) * 1024 + hk * 128];
  const u16* gV = &VT[(size_t)(hk * 128 + wave * 32 + (lane >> 3)) * 4096 + b * 2048 +
                      (((lane & 7) * 8) ^ ((lane >> 3) << 3))];

  int kOff[2][8], vOff[4][4];
#pragma unroll
  for (int kvt = 0; kvt < 2; kvt++) {
    const int row = kvt * 32 + l31;
#pragma unroll
    for (int ks = 0; ks < 8; ks++)
      kOff[kvt][ks] = row * 128 + ((ks * 16 + hi * 8) ^ ((row & 7) << 3));
  }
#pragma unroll
  for (int dt = 0; dt < 4; dt++) {
    const int row = dt * 32 + l31;
#pragma unroll
    for (int kvs = 0; kvs < 4; kvs++)
      vOff[dt][kvs] = row * 64 + ((kvs * 16 + hi * 8) ^ ((row & 7) << 3));
  }

  STAGE_K(0, 0);
  STAGE_V(0, 0);

  bf16x8 qf[8];
#pragma unroll
  for (int ks = 0; ks < 8; ks++)
    qf[ks] = *(const bf16x8*)&QO[(size_t)(qrow0 + l31) * 4096 + h * 128 + ks * 16 + hi * 8];

  f32x16 o[4] = {};
  float mrun = -3.0e38f, lrun = 0.0f;
  u32 fw[4][4];

  __syncthreads();

  for (int t = 0; t < 32; t++) {
    const int kb = t & 1;
    if (t < 31) {
      STAGE_K(kb ^ 1, t + 1);
      STAGE_V((t + 1) % 3, t + 1);
    }

    f32x16 st[2] = {};
    __builtin_amdgcn_s_setprio(1);
#pragma unroll
    for (int ks = 0; ks < 8; ks++) {
#pragma unroll
      for (int kvt = 0; kvt < 2; kvt++) {
        bf16x8 kf = *(const bf16x8*)&KsF[kb * 8192 + kOff[kvt][ks]];
        st[kvt] = MFMA32(kf, qf[ks], st[kvt]);
      }
    }
    __builtin_amdgcn_s_setprio(0);

    if (t > 0) PV_STEP((t - 1) % 3);

    float m8[8];
#pragma unroll
    for (int r = 0; r < 8; r++)
      m8[r] = fmaxf(fmaxf(fmaxf(st[0][r], st[0][r + 8]), st[1][r]), st[1][r + 8]);
    float mA = fmaxf(fmaxf(m8[0], m8[1]), m8[2]);
    mA = fmaxf(fmaxf(mA, m8[3]), m8[4]);
    mA = fmaxf(fmaxf(mA, m8[5]), m8[6]);
    mA = fmaxf(mA, m8[7]);
    i32x2 mr = __builtin_amdgcn_permlane32_swap(__float_as_int(mA), __float_as_int(mA),
                                                false, false);
    const float mx = fmaxf(__int_as_float(mr[0]), __int_as_float(mr[1]));
    const float mxs = mx * scl2;
    if (__any(mxs > mrun + 8.0f)) {
      const float mn = fmaxf(mrun, mxs);
      const float alpha = __builtin_amdgcn_exp2f(mrun - mn);
      mrun = mn;
      lrun *= alpha;
#pragma unroll
      for (int re = 0; re < 16; re++) {
        const float av = __shfl(alpha, (re & 3) + 8 * (re >> 2) + 4 * hi, 64);
#pragma unroll
        for (int dt = 0; dt < 4; dt++) o[dt][re] *= av;
      }
    }
    float rsa[4] = {0.f, 0.f, 0.f, 0.f};
#pragma unroll
    for (int kvt = 0; kvt < 2; kvt++)
#pragma unroll
      for (int r = 0; r < 16; r++) {
        const float p = __builtin_amdgcn_exp2f(fmaf(st[kvt][r], scl2, -mrun));
        st[kvt][r] = p;
        rsa[r & 3] += p;
      }
    float rs = (rsa[0] + rsa[1]) + (rsa[2] + rsa[3]);
    i32x2 rr = __builtin_amdgcn_permlane32_swap(__float_as_int(rs), __float_as_int(rs),
                                                false, false);
    lrun += __int_as_float(rr[0]) + __int_as_float(rr[1]);

    u32 W0[8], W1[8];
#pragma unroll
    for (int rp = 0; rp < 8; rp++) {
      W0[rp] = pk2(st[0][2 * rp], st[0][2 * rp + 1]);
      W1[rp] = pk2(st[1][2 * rp], st[1][2 * rp + 1]);
    }
#pragma unroll
    for (int kvs = 0; kvs < 4; kvs++) {
#pragma unroll
      for (int sl = 0; sl < 2; sl++) {
        const u32 wa = (kvs < 2) ? W0[4 * (kvs & 1) + sl] : W1[4 * (kvs & 1) + sl];
        const u32 wb = (kvs < 2) ? W0[4 * (kvs & 1) + 2 + sl] : W1[4 * (kvs & 1) + 2 + sl];
        i32x2 r = __builtin_amdgcn_permlane32_swap((int)wa, (int)wb, false, false);
        fw[kvs][sl] = (u32)r[0];
        fw[kvs][2 + sl] = (u32)r[1];
      }
    }

    __syncthreads();
  }

  PV_STEP(1);  // final deferred PV(31): buffer 31 % 3 = 1

  const float invl = 1.0f / lrun;
#pragma unroll
  for (int re = 0; re < 16; re++) {
    const int qv = (re & 3) + 8 * (re >> 2) + 4 * hi;
    const float il = __shfl(invl, qv, 64);
    const size_t rowb = (size_t)(qrow0 + qv) * 4096 + h * 128;
#pragma unroll
    for (int dt = 0; dt < 4; dt++)
      QO[rowb + dt * 32 + l31] = f2b(o[dt][re] * il);
  }
}

// ---------------------------------------------------------------------------
extern "C" void kernel_launch(void* const* d_in, const int* in_sizes, int n_in,
                              void* d_out, int out_size, void* d_ws, size_t ws_size,
                              hipStream_t stream) {
  (void)in_sizes; (void)n_in; (void)out_size; (void)ws_size;
  const float* x    = (const float*)d_in[0];
  const float* wq_w = (const float*)d_in[1];
  const float* wq_b = (const float*)d_in[2];
  const float* wk_w = (const float*)d_in[3];
  const float* wk_b = (const float*)d_in[4];
  const float* wv_w = (const float*)d_in[5];
  const float* wv_b = (const float*)d_in[6];
  const float* wo_w = (const float*)d_in[7];
  const float* wo_b = (const float*)d_in[8];
  float* out = (float*)d_out;
  char* ws = (char*)d_ws;
  char* od = (char*)d_out;

  u16* TQ  = (u16*)(ws);             // 32 MiB: wq^T bf16; later wo^T bf16
  u16* QA  = (u16*)(ws + 33554432);  // 32 MiB: Q bf16, then attn-out (in place)
  u16* Xb  = (u16*)(od);             // 32 MiB: x bf16
  u16* TK  = (u16*)(od + 33554432);  //  8 MiB: wk^T bf16
  u16* TV  = (u16*)(od + 41943040);  //  8 MiB: wv^T bf16
  u16* Kb  = (u16*)(od + 50331648);  //  8 MiB: K bf16
  u16* VTb = (u16*)(od + 58720256);  //  8 MiB: V^T bf16

  cast_f32_bf16<<<8192, 256, 0, stream>>>(x, Xb, 16777216);
  transpose_cast<<<dim3(128, 128), 256, 0, stream>>>(wq_w, TQ, 4096, 4096);
  transpose_cast<<<dim3(32, 128), 256, 0, stream>>>(wk_w, TK, 4096, 1024);
  transpose_cast<<<dim3(32, 128), 256, 0, stream>>>(wv_w, TV, 4096, 1024);

  gemm256<0><<<256, 512, 0, stream>>>(Xb, TQ, wq_b, QA);
  gemm_bt<0, 0><<<dim3(8, 32), 256, 0, stream>>>(Xb, TK, wk_b, Kb, 4096, 1024);
  gemm_bt<1, 0><<<dim3(8, 32), 256, 0, stream>>>(Xb, TV, wv_b, VTb, 4096, 1024);

  // wo^T into TQ region — stream-ordered after the Q GEMM that read TQ
  transpose_cast<<<dim3(128, 128), 256, 0, stream>>>(wo_w, TQ, 4096, 4096);

  flash_gqa<<<dim3(1024), 256, 0, stream>>>(Kb, VTb, QA);

  // final: reads only ws (QA, TQ) + wo_b; overwrites all of d_out with fp32
  gemm256<1><<<256, 512, 0, stream>>>(QA, TQ, wo_b, out);
}